// Round 7
// baseline (10754.427 us; speedup 1.0000x reference)
//
#include <hip/hip_runtime.h>

#define N 4096
#define IN_DIM 128
#define T_STEPS 2048
#define KSLOTS 576           // uniform padded ELL row width; max nnz ~490 (mean 409.6, sd 19.2)
#define CHUNKS (KSLOTS / 64) // 9, uniform for all rows
#define NBLOCKS 128
#define NTHREADS 1024
#define ROWS_PER_WAVE 2
#define ROWS_PER_BLOCK (ROWS_PER_WAVE * (NTHREADS / 64))   // 32
#define SENTINEL_BITS 0x7FC00001u   // qNaN; h is always finite -> producers never write this

typedef float f32x4 __attribute__((ext_vector_type(4)));
typedef unsigned int u32x2 __attribute__((ext_vector_type(2)));

// ---------------------------------------------------------------------------
// Kernel 0: poison out with qNaN sentinel (replay tripwire, proven) and set
// flags to 0xFFFFFFFF (never an awaited value). Flag protocol awaits values
// in {1..2047}; stale end-of-replay value is 2048 and first-launch poison is
// 0xAAAAAAAA — neither can false-pass, so no init-ordering hazard exists.
// ---------------------------------------------------------------------------
__global__ void init_sentinel(float* __restrict__ out, unsigned int* __restrict__ flags) {
    const size_t i = (size_t)blockIdx.x * blockDim.x + threadIdx.x;
    __hip_atomic_store(&out[i], __uint_as_float(SENTINEL_BITS),
                       __ATOMIC_RELAXED, __HIP_MEMORY_SCOPE_AGENT);
    if (i < NBLOCKS)
        __hip_atomic_store(&flags[i], 0xFFFFFFFFu,
                           __ATOMIC_RELAXED, __HIP_MEMORY_SCOPE_AGENT);
}

// ---------------------------------------------------------------------------
// Kernel 1: dense W -> uniform padded ELL with bank-aware chunk assignment
// (each 64-slot chunk hits every LDS bank ~2x; 2-way is free on gfx950).
// Padding: val=0, col=0 (same-address broadcast, free). Unchanged since R2.
// ---------------------------------------------------------------------------
__global__ void build_ell(const float* __restrict__ W,
                          float* __restrict__ vals,
                          unsigned short* __restrict__ cols) {
    __shared__ float sval[KSLOTS];
    __shared__ unsigned short scol[KSLOTS];
    __shared__ float slot_val[KSLOTS];
    __shared__ unsigned short slot_col[KSLOTS];
    __shared__ int chunk_fill[CHUNKS];
    __shared__ int cnt;

    const int r = blockIdx.x;
    const int tid = threadIdx.x;
    if (tid == 0) cnt = 0;
    if (tid < CHUNKS) chunk_fill[tid] = 0;
    __syncthreads();

    const float* wrow = W + (size_t)r * N;
    for (int j = tid; j < N; j += blockDim.x) {
        float w = wrow[j];
        if (w != 0.0f) {
            int p = atomicAdd(&cnt, 1);
            if (p < KSLOTS) { sval[p] = w; scol[p] = (unsigned short)j; }
        }
    }
    __syncthreads();
    for (int j = tid; j < KSLOTS; j += blockDim.x) { slot_val[j] = 0.0f; slot_col[j] = 0; }
    __syncthreads();

    if (tid < 32) {  // one thread per bank spreads its entries across chunks
        int k = 0;
        const int n = (cnt < KSLOTS) ? cnt : KSLOTS;
        for (int p = 0; p < n; ++p) {
            int c = scol[p];
            if ((c & 31) == tid) {
                int ch0 = (k + tid) % CHUNKS;
                for (int probe = 0; probe < CHUNKS; ++probe) {
                    int cc = ch0 + probe; if (cc >= CHUNKS) cc -= CHUNKS;
                    int pos = atomicAdd(&chunk_fill[cc], 1);
                    if (pos < 64) {
                        slot_val[cc * 64 + pos] = sval[p];
                        slot_col[cc * 64 + pos] = (unsigned short)c;
                        break;
                    }
                }
                ++k;
            }
        }
    }
    __syncthreads();

    float* vrow = vals + (size_t)r * KSLOTS;
    unsigned short* crow = cols + (size_t)r * KSLOTS;
    for (int j = tid; j < KSLOTS; j += blockDim.x) { vrow[j] = slot_val[j]; crow[j] = slot_col[j]; }
}

// ---------------------------------------------------------------------------
// Coherent accesses straight at the coherence point (bypass L1+L2).
// All device-scope (sc0 sc1) — the ONLY scope used anywhere (R15 lesson).
// ---------------------------------------------------------------------------
__device__ __forceinline__ f32x4 load_coherent_x4(const float* p) {
    f32x4 v;
    asm volatile("global_load_dwordx4 %0, %1, off sc0 sc1\n\t"
                 "s_waitcnt vmcnt(0)"
                 : "=v"(v) : "v"(p) : "memory");
    return v;
}

__device__ __forceinline__ void store_coherent_x4(float* p, f32x4 v) {
    asm volatile("global_store_dwordx4 %0, %1, off sc0 sc1"
                 :: "v"(p), "v"(v) : "memory");
}

__device__ __forceinline__ u32x2 load_coherent_u32x2(const unsigned int* p) {
    u32x2 v;
    asm volatile("global_load_dwordx2 %0, %1, off sc0 sc1\n\t"
                 "s_waitcnt vmcnt(0)"
                 : "=v"(v) : "v"(p) : "memory");
    return v;
}

__device__ __forceinline__ void store_coherent_u32(unsigned int* p, unsigned int v) {
    asm volatile("global_store_dword %0, %1, off sc0 sc1"
                 :: "v"(p), "v"(v) : "memory");
}

__device__ __forceinline__ bool granule_not_ready(f32x4 hv) {
    return (__float_as_uint(hv.x) == SENTINEL_BITS) |
           (__float_as_uint(hv.y) == SENTINEL_BITS) |
           (__float_as_uint(hv.z) == SENTINEL_BITS) |
           (__float_as_uint(hv.w) == SENTINEL_BITS);
}

// Branch-free tanh (validated R6-first-launch + R9: absmax 3.9e-3 unchanged).
__device__ __forceinline__ float fast_tanh(float v) {
    float ax = __builtin_fabsf(v);
    float e  = __builtin_amdgcn_exp2f(ax * 2.88539008177793f);  // 2*log2(e)
    float r  = 1.0f - 2.0f * __builtin_amdgcn_rcpf(e + 1.0f);
    return __builtin_copysignf(r, v);
}

// ---------------------------------------------------------------------------
// Kernel 2: persistent step kernel. R16 = R13's proven skeleton (128 blocks,
// 2 rows/wave, hout collect, wave-emitted full-line sc0 sc1 store) with
// cheap flag-based detection replacing the expensive data re-poll:
//   PRODUCER (wave 1): stores the block's 128B out-line (8 lanes dwordx4),
//     s_waitcnt vmcnt(0) (line ACKED at the MALL), then lane 0 plain-stores
//     flags[blockIdx] = t+1 (completed-count; no RMW, own flag only).
//   CONSUMER (wave 0): polls all 128 flags with one dwordx2/lane (512B per
//     round per block = 64KB/round chip-wide, 32x less than data re-poll),
//     __all-ballot across the wave, bounded at 64 rounds; then barrier
//     releases the block and every thread bulk-loads its 16B granule ONCE.
//   FALLBACK: the R13 per-granule sentinel poll survives after the flag
//     gate (0 iterations in normal operation) -> structurally unhangable,
//     degrades to R13 semantics if flags ever misbehave. qNaN poison kept.
// Flag visibility: store(out) -> vmcnt(0) ACK -> store(flag) at one scope
// (MALL) means flag==t implies out[t-1] readable. No XCD topology, no
// L2-scope ops, no atomic fan-in, workspace +512B only (R15 lessons).
// ---------------------------------------------------------------------------
__global__ void __launch_bounds__(NTHREADS, 1) esn_steps(
    const float* __restrict__ x,
    const float* __restrict__ W_in,
    const float* __restrict__ vals,
    const unsigned short* __restrict__ cols,
    float* __restrict__ out,
    unsigned int* __restrict__ flags) {

    __shared__ float h_lds[N];       // full previous state, 16 KB
    __shared__ float x_lds[IN_DIM];
    __shared__ __align__(16) float hout[ROWS_PER_BLOCK];  // block's 32 new rows

    const int tid  = threadIdx.x;
    const int lane = tid & 63;
    const int wave = tid >> 6;
    const int blockBase = blockIdx.x * ROWS_PER_BLOCK;
    const int base = blockBase + wave * ROWS_PER_WAVE;  // 2 rows/wave

    // Per-row W_in slices.
    float w0[ROWS_PER_WAVE], w1[ROWS_PER_WAVE];
    #pragma unroll
    for (int j = 0; j < ROWS_PER_WAVE; ++j) {
        w0[j] = W_in[(base + j) * IN_DIM + lane];
        w1[j] = W_in[(base + j) * IN_DIM + 64 + lane];
    }

    // Hoist the 2-row ELL slice into registers (18 vals + 18 byte offsets).
    float rv[ROWS_PER_WAVE][CHUNKS];
    int   rc[ROWS_PER_WAVE][CHUNKS];
    #pragma unroll
    for (int j = 0; j < ROWS_PER_WAVE; ++j) {
        const float* vp = vals + (size_t)(base + j) * KSLOTS;
        const unsigned short* cp = cols + (size_t)(base + j) * KSLOTS;
        #pragma unroll
        for (int i = 0; i < CHUNKS; ++i) {
            rv[j][i] = vp[(i << 6) + lane];
            rc[j][i] = ((int)cp[(i << 6) + lane]) << 2;
        }
    }

    const int i4 = tid << 2;

    for (int t = 0; t < T_STEPS; ++t) {
        // ---- stage x_t on the LAST two waves (overlaps detection) ----
        if (tid >= NTHREADS - IN_DIM) {
            const int xi = tid - (NTHREADS - IN_DIM);
            x_lds[xi] = x[t * IN_DIM + xi];
        }

        // ---- detect + stage h_{t-1} ----
        f32x4 hv;
        if (t > 0) {
            if (wave == 0) {
                // Flag gate: all 128 producer flags must equal t.
                const unsigned int* fp = flags + (lane << 1);
                const unsigned int want = (unsigned int)t;
                __builtin_amdgcn_s_sleep(8);       // producers can't finish earlier
                int guard = 0;
                for (;;) {
                    u32x2 f = load_coherent_u32x2(fp);
                    bool ok = (f.x == want) && (f.y == want);
                    if (__all(ok)) break;
                    if (++guard > 64) break;       // unhangable: sentinel path below
                    __builtin_amdgcn_s_sleep(2);
                }
            }
            __syncthreads();   // barrier 0: flags confirmed for the whole block

            // One-shot bulk load (sentinel fallback: 0 iterations normally).
            const float* addr = out + (size_t)(t - 1) * N + i4;
            hv = load_coherent_x4(addr);
            while (granule_not_ready(hv)) {
                __builtin_amdgcn_s_sleep(4);
                hv = load_coherent_x4(addr);
            }
        } else {
            hv = (f32x4)(0.0f);
        }
        ((f32x4*)h_lds)[tid] = hv;
        __syncthreads();   // barrier 1: h_lds (and x_lds) fully staged

        // ---- 2 row dots: input part + register-ELL sparse gather ----
        float acc[ROWS_PER_WAVE];
        const float xa = x_lds[lane], xb = x_lds[64 + lane];
        #pragma unroll
        for (int j = 0; j < ROWS_PER_WAVE; ++j) acc[j] = w0[j] * xa + w1[j] * xb;

        #pragma unroll
        for (int j = 0; j < ROWS_PER_WAVE; ++j) {
            #pragma unroll
            for (int i = 0; i < CHUNKS; ++i) {
                acc[j] += rv[j][i] * *(const float*)((const char*)h_lds + rc[j][i]);
            }
        }

        // butterfly reduce each acc[j] across the wave
        #pragma unroll
        for (int j = 0; j < ROWS_PER_WAVE; ++j) {
            #pragma unroll
            for (int off = 32; off > 0; off >>= 1)
                acc[j] += __shfl_xor(acc[j], off);
        }

        // lanes 0..1 finalize into the LDS collect buffer (one row each)
        if (lane < ROWS_PER_WAVE) {
            float a = (lane == 0) ? acc[0] : acc[1];
            float hp = h_lds[base + lane];
            float hn = 0.7f * hp + 0.3f * fast_tanh(a);
            hout[wave * ROWS_PER_WAVE + lane] = hn;
        }
        __syncthreads();   // barrier 2: collect done + all h_lds reads done

        // ---- PUBLISH (wave 1, so wave 0 can poll immediately): one coalesced
        //      128B line store, drain to ACK, then own-flag plain store ----
        if (wave == 1) {
            if (lane < ROWS_PER_BLOCK / 4) {
                f32x4 hv4 = ((const f32x4*)hout)[lane];
                store_coherent_x4(out + (size_t)t * N + blockBase + (lane << 2), hv4);
            }
            asm volatile("s_waitcnt vmcnt(0)" ::: "memory");  // line ACKED at MALL
            if (lane == 0)
                store_coherent_u32(&flags[blockIdx.x], (unsigned int)(t + 1));
        }
    }
}

// ---------------------------------------------------------------------------
// Workspace layout (bytes):
//   [0, +N*KSLOTS*4)       ELL vals (f32)   9.44 MB
//   [.., +N*KSLOTS*2)      ELL cols (u16)   4.72 MB
//   [.., +512)             per-block completion flags (u32[128])
// ---------------------------------------------------------------------------
extern "C" void kernel_launch(void* const* d_in, const int* in_sizes, int n_in,
                              void* d_out, int out_size, void* d_ws, size_t ws_size,
                              hipStream_t stream) {
    const float* x    = (const float*)d_in[0];  // [2048,128]
    const float* W_in = (const float*)d_in[1];  // [4096,128]
    const float* W    = (const float*)d_in[2];  // [4096,4096]
    float* out = (float*)d_out;                 // [2048,4096]

    char* ws = (char*)d_ws;
    float* vals = (float*)ws;
    unsigned short* cols = (unsigned short*)(ws + (size_t)N * KSLOTS * 4);
    unsigned int* flags = (unsigned int*)(ws + (size_t)N * KSLOTS * 6);  // 14,155,776: aligned

    init_sentinel<<<(T_STEPS * N) / NTHREADS, NTHREADS, 0, stream>>>(out, flags);
    build_ell<<<N, 256, 0, stream>>>(W, vals, cols);

    void* args[] = {(void*)&x, (void*)&W_in, (void*)&vals, (void*)&cols,
                    (void*)&out, (void*)&flags};
    hipLaunchCooperativeKernel((void*)esn_steps, dim3(NBLOCKS), dim3(NTHREADS),
                               args, 0, stream);
}

// Round 9
// 4703.491 us; speedup vs baseline: 2.2865x; 2.2865x over previous
//
#include <hip/hip_runtime.h>

#define N 4096
#define IN_DIM 128
#define T_STEPS 2048
#define KSLOTS 576           // uniform padded ELL row width; max nnz ~490 (mean 409.6, sd 19.2)
#define CHUNKS (KSLOTS / 64) // 9, uniform for all rows
#define NBLOCKS 128
#define NTHREADS 1024
#define ROWS_PER_WAVE 2
#define ROWS_PER_BLOCK (ROWS_PER_WAVE * (NTHREADS / 64))   // 32
#define SENTINEL_BITS 0x7FC00001u   // qNaN; h is always finite -> producers never write this

typedef float f32x4 __attribute__((ext_vector_type(4)));

// ---------------------------------------------------------------------------
// Kernel 0: fill out with the sentinel, write-through (agent scope) so it is
// at the coherence point before any step-kernel poll. Defends against 0xAA
// poison and stale floats from a previous replay (both non-sentinel).
// ---------------------------------------------------------------------------
__global__ void init_sentinel(float* __restrict__ out) {
    const size_t i = (size_t)blockIdx.x * blockDim.x + threadIdx.x;
    __hip_atomic_store(&out[i], __uint_as_float(SENTINEL_BITS),
                       __ATOMIC_RELAXED, __HIP_MEMORY_SCOPE_AGENT);
}

// ---------------------------------------------------------------------------
// Kernel 1: dense W -> uniform padded ELL with bank-aware chunk assignment
// (each 64-slot chunk hits every LDS bank ~2x; 2-way is free on gfx950).
// Padding: val=0, col=0 (same-address broadcast, free). Unchanged since R2.
// ---------------------------------------------------------------------------
__global__ void build_ell(const float* __restrict__ W,
                          float* __restrict__ vals,
                          unsigned short* __restrict__ cols) {
    __shared__ float sval[KSLOTS];
    __shared__ unsigned short scol[KSLOTS];
    __shared__ float slot_val[KSLOTS];
    __shared__ unsigned short slot_col[KSLOTS];
    __shared__ int chunk_fill[CHUNKS];
    __shared__ int cnt;

    const int r = blockIdx.x;
    const int tid = threadIdx.x;
    if (tid == 0) cnt = 0;
    if (tid < CHUNKS) chunk_fill[tid] = 0;
    __syncthreads();

    const float* wrow = W + (size_t)r * N;
    for (int j = tid; j < N; j += blockDim.x) {
        float w = wrow[j];
        if (w != 0.0f) {
            int p = atomicAdd(&cnt, 1);
            if (p < KSLOTS) { sval[p] = w; scol[p] = (unsigned short)j; }
        }
    }
    __syncthreads();
    for (int j = tid; j < KSLOTS; j += blockDim.x) { slot_val[j] = 0.0f; slot_col[j] = 0; }
    __syncthreads();

    if (tid < 32) {  // one thread per bank spreads its entries across chunks
        int k = 0;
        const int n = (cnt < KSLOTS) ? cnt : KSLOTS;
        for (int p = 0; p < n; ++p) {
            int c = scol[p];
            if ((c & 31) == tid) {
                int ch0 = (k + tid) % CHUNKS;
                for (int probe = 0; probe < CHUNKS; ++probe) {
                    int cc = ch0 + probe; if (cc >= CHUNKS) cc -= CHUNKS;
                    int pos = atomicAdd(&chunk_fill[cc], 1);
                    if (pos < 64) {
                        slot_val[cc * 64 + pos] = sval[p];
                        slot_col[cc * 64 + pos] = (unsigned short)c;
                        break;
                    }
                }
                ++k;
            }
        }
    }
    __syncthreads();

    float* vrow = vals + (size_t)r * KSLOTS;
    unsigned short* crow = cols + (size_t)r * KSLOTS;
    for (int j = tid; j < KSLOTS; j += blockDim.x) { vrow[j] = slot_val[j]; crow[j] = slot_col[j]; }
}

// ---------------------------------------------------------------------------
// Coherent 16B accesses straight at the coherence point (bypass L1+L2).
// Load/store forms are R4/R9/R11-proven. ISSUE_X4 issues WITHOUT waiting —
// used only by the pipelined poll, which manages vmcnt counts explicitly.
// ---------------------------------------------------------------------------
__device__ __forceinline__ void store_coherent_x4(float* p, f32x4 v) {
    asm volatile("global_store_dwordx4 %0, %1, off sc0 sc1"
                 :: "v"(p), "v"(v) : "memory");
}

#define ISSUE_X4(dst, p) \
    asm volatile("global_load_dwordx4 %0, %1, off sc0 sc1" \
                 : "=v"(dst) : "v"(p) : "memory")

__device__ __forceinline__ bool granule_not_ready(f32x4 hv) {
    return (__float_as_uint(hv.x) == SENTINEL_BITS) |
           (__float_as_uint(hv.y) == SENTINEL_BITS) |
           (__float_as_uint(hv.z) == SENTINEL_BITS) |
           (__float_as_uint(hv.w) == SENTINEL_BITS);
}

// Branch-free tanh (validated R6-first-launch + R9: absmax 3.9e-3 unchanged).
__device__ __forceinline__ float fast_tanh(float v) {
    float ax = __builtin_fabsf(v);
    float e  = __builtin_amdgcn_exp2f(ax * 2.88539008177793f);  // 2*log2(e)
    float r  = 1.0f - 2.0f * __builtin_amdgcn_rcpf(e + 1.0f);
    return __builtin_copysignf(r, v);
}

// ---------------------------------------------------------------------------
// Kernel 2: persistent step kernel — R13's proven skeleton (128 blocks,
// 2 rows/wave, hout collect, wave-0 full-line sc0 sc1 store, qNaN
// data-as-flag). R18 single-variable change: the poll's detection tail.
// R13's loop sampled at period sleep(256)+RT(~700) ~= 950cy because each
// sample serialized load+vmcnt(0). R18 keeps TWO loads in flight and waits
// vmcnt(1) (only the older), checking slots alternately: sampling period
// ~(RT+2*sleep)/2 ~= 480cy -> expected detect-after-arrival drops ~250-400cy
// on the critical tail granule. Per-lane adaptive (ready lanes exit).
// Register-WAR safety: exactly ONE poll load is in flight at loop exit; it
// is drained by vmcnt(0)+keep-alive AFTER the gather/reduce (~700cy later,
// where vmcnt is naturally 0 -> free). sched_barrier(0) after every counted
// wait per the compiler-hoisting hazard (inline-asm waitcnt rule #18).
// ---------------------------------------------------------------------------
__global__ void __launch_bounds__(NTHREADS, 1) esn_steps(
    const float* __restrict__ x,
    const float* __restrict__ W_in,
    const float* __restrict__ vals,
    const unsigned short* __restrict__ cols,
    float* __restrict__ out) {

    __shared__ float h_lds[N];       // full previous state, 16 KB
    __shared__ float x_lds[IN_DIM];
    __shared__ __align__(16) float hout[ROWS_PER_BLOCK];  // block's 32 new rows

    const int tid  = threadIdx.x;
    const int lane = tid & 63;
    const int wave = tid >> 6;
    const int blockBase = blockIdx.x * ROWS_PER_BLOCK;
    const int base = blockBase + wave * ROWS_PER_WAVE;  // 2 rows/wave

    // Per-row W_in slices.
    float w0[ROWS_PER_WAVE], w1[ROWS_PER_WAVE];
    #pragma unroll
    for (int j = 0; j < ROWS_PER_WAVE; ++j) {
        w0[j] = W_in[(base + j) * IN_DIM + lane];
        w1[j] = W_in[(base + j) * IN_DIM + 64 + lane];
    }

    // Hoist the 2-row ELL slice into registers (18 vals + 18 byte offsets).
    float rv[ROWS_PER_WAVE][CHUNKS];
    int   rc[ROWS_PER_WAVE][CHUNKS];
    #pragma unroll
    for (int j = 0; j < ROWS_PER_WAVE; ++j) {
        const float* vp = vals + (size_t)(base + j) * KSLOTS;
        const unsigned short* cp = cols + (size_t)(base + j) * KSLOTS;
        #pragma unroll
        for (int i = 0; i < CHUNKS; ++i) {
            rv[j][i] = vp[(i << 6) + lane];
            rc[j][i] = ((int)cp[(i << 6) + lane]) << 2;
        }
    }

    const int i4 = tid << 2;

    for (int t = 0; t < T_STEPS; ++t) {
        // ---- stage x_t on the LAST two waves (overlaps the poll) ----
        if (tid >= NTHREADS - IN_DIM) {
            const int xi = tid - (NTHREADS - IN_DIM);
            x_lds[xi] = x[t * IN_DIM + xi];
        }

        // ---- stage h_{t-1}: dual-slot pipelined coherent poll (R18) ----
        f32x4 hv;
        f32x4 a = (f32x4)(0.0f), b = (f32x4)(0.0f);
        const bool polled = (t > 0);
        if (polled) {
            const float* addr = out + (size_t)(t - 1) * N + i4;
            __builtin_amdgcn_s_sleep(8);           // skip guaranteed-miss window
            // Normalize the wave's vmem counter (prev-iter store / x staging
            // ACKs overlap the sleep above; typically instant).
            asm volatile("s_waitcnt vmcnt(0)" ::: "memory");
            ISSUE_X4(a, addr);
            __builtin_amdgcn_s_sleep(2);
            ISSUE_X4(b, addr);
            for (;;) {
                asm volatile("s_waitcnt vmcnt(1)" ::: "memory");  // slot A done
                __builtin_amdgcn_sched_barrier(0);
                if (!granule_not_ready(a)) { hv = a; break; }
                __builtin_amdgcn_s_sleep(2);
                ISSUE_X4(a, addr);
                asm volatile("s_waitcnt vmcnt(1)" ::: "memory");  // slot B done
                __builtin_amdgcn_sched_barrier(0);
                if (!granule_not_ready(b)) { hv = b; break; }
                __builtin_amdgcn_s_sleep(2);
                ISSUE_X4(b, addr);
            }
        } else {
            hv = (f32x4)(0.0f);
        }
        ((f32x4*)h_lds)[tid] = hv;
        __syncthreads();   // barrier 1: h_lds (and x_lds) fully staged

        // ---- 2 row dots: input part + register-ELL sparse gather ----
        float acc[ROWS_PER_WAVE];
        const float xa = x_lds[lane], xb = x_lds[64 + lane];
        #pragma unroll
        for (int j = 0; j < ROWS_PER_WAVE; ++j) acc[j] = w0[j] * xa + w1[j] * xb;

        #pragma unroll
        for (int j = 0; j < ROWS_PER_WAVE; ++j) {
            #pragma unroll
            for (int i = 0; i < CHUNKS; ++i) {
                acc[j] += rv[j][i] * *(const float*)((const char*)h_lds + rc[j][i]);
            }
        }

        // butterfly reduce each acc[j] across the wave
        #pragma unroll
        for (int j = 0; j < ROWS_PER_WAVE; ++j) {
            #pragma unroll
            for (int off = 32; off > 0; off >>= 1)
                acc[j] += __shfl_xor(acc[j], off);
        }

        // ---- drain the one leftover poll load (issued >=~700cy ago -> free)
        //      and keep a/b alive until here so no WAR clobber is possible ----
        if (polled) {
            asm volatile("s_waitcnt vmcnt(0)" ::: "memory");
            __builtin_amdgcn_sched_barrier(0);
            asm volatile("" :: "v"(a), "v"(b));
        }

        // lanes 0..1 finalize into the LDS collect buffer (one row each)
        if (lane < ROWS_PER_WAVE) {
            float aa = (lane == 0) ? acc[0] : acc[1];
            float hp = h_lds[base + lane];
            float hn = 0.7f * hp + 0.3f * fast_tanh(aa);
            hout[wave * ROWS_PER_WAVE + lane] = hn;
        }
        __syncthreads();   // barrier 2: collect done + all h_lds reads done

        // ---- wave 0 emits the block's 32 rows as one coalesced 128B store;
        //      the other 15 waves proceed straight to the next step's poll ----
        if (tid < ROWS_PER_BLOCK / 4) {
            f32x4 hv4 = ((const f32x4*)hout)[tid];
            store_coherent_x4(out + (size_t)t * N + blockBase + (tid << 2), hv4);
        }
    }
}

// ---------------------------------------------------------------------------
// Workspace layout (bytes):
//   [0, +N*KSLOTS*4)       ELL vals (f32)   9.44 MB
//   [.., +N*KSLOTS*2)      ELL cols (u16)   4.72 MB
// ---------------------------------------------------------------------------
extern "C" void kernel_launch(void* const* d_in, const int* in_sizes, int n_in,
                              void* d_out, int out_size, void* d_ws, size_t ws_size,
                              hipStream_t stream) {
    const float* x    = (const float*)d_in[0];  // [2048,128]
    const float* W_in = (const float*)d_in[1];  // [4096,128]
    const float* W    = (const float*)d_in[2];  // [4096,4096]
    float* out = (float*)d_out;                 // [2048,4096]

    char* ws = (char*)d_ws;
    float* vals = (float*)ws;
    unsigned short* cols = (unsigned short*)(ws + (size_t)N * KSLOTS * 4);

    init_sentinel<<<(T_STEPS * N) / NTHREADS, NTHREADS, 0, stream>>>(out);
    build_ell<<<N, 256, 0, stream>>>(W, vals, cols);

    void* args[] = {(void*)&x, (void*)&W_in, (void*)&vals, (void*)&cols, (void*)&out};
    hipLaunchCooperativeKernel((void*)esn_steps, dim3(NBLOCKS), dim3(NTHREADS),
                               args, 0, stream);
}

// Round 10
// 3267.469 us; speedup vs baseline: 3.2914x; 1.4395x over previous
//
#include <hip/hip_runtime.h>

#define N 4096
#define IN_DIM 128
#define T_STEPS 2048
#define KSLOTS 576           // uniform padded ELL row width; max nnz ~490 (mean 409.6, sd 19.2)
#define CHUNKS (KSLOTS / 64) // 9, uniform for all rows
#define NBLOCKS 128
#define NTHREADS 1024
#define ROWS_PER_WAVE 2
#define ROWS_PER_BLOCK (ROWS_PER_WAVE * (NTHREADS / 64))   // 32
#define SENTINEL_BITS 0x7FC00001u   // qNaN; h is always finite -> producers never write this

typedef float f32x4 __attribute__((ext_vector_type(4)));

// ---------------------------------------------------------------------------
// Kernel 0: fill out with the sentinel, write-through (agent scope) so it is
// at the coherence point before any step-kernel poll. Defends against 0xAA
// poison and stale floats from a previous replay (both non-sentinel).
// ---------------------------------------------------------------------------
__global__ void init_sentinel(float* __restrict__ out) {
    const size_t i = (size_t)blockIdx.x * blockDim.x + threadIdx.x;
    __hip_atomic_store(&out[i], __uint_as_float(SENTINEL_BITS),
                       __ATOMIC_RELAXED, __HIP_MEMORY_SCOPE_AGENT);
}

// ---------------------------------------------------------------------------
// Kernel 1: dense W -> uniform padded ELL with bank-aware chunk assignment
// (each 64-slot chunk hits every LDS bank ~2x; 2-way is free on gfx950).
// Padding: val=0, col=0 (same-address broadcast, free). Unchanged since R2.
// ---------------------------------------------------------------------------
__global__ void build_ell(const float* __restrict__ W,
                          float* __restrict__ vals,
                          unsigned short* __restrict__ cols) {
    __shared__ float sval[KSLOTS];
    __shared__ unsigned short scol[KSLOTS];
    __shared__ float slot_val[KSLOTS];
    __shared__ unsigned short slot_col[KSLOTS];
    __shared__ int chunk_fill[CHUNKS];
    __shared__ int cnt;

    const int r = blockIdx.x;
    const int tid = threadIdx.x;
    if (tid == 0) cnt = 0;
    if (tid < CHUNKS) chunk_fill[tid] = 0;
    __syncthreads();

    const float* wrow = W + (size_t)r * N;
    for (int j = tid; j < N; j += blockDim.x) {
        float w = wrow[j];
        if (w != 0.0f) {
            int p = atomicAdd(&cnt, 1);
            if (p < KSLOTS) { sval[p] = w; scol[p] = (unsigned short)j; }
        }
    }
    __syncthreads();
    for (int j = tid; j < KSLOTS; j += blockDim.x) { slot_val[j] = 0.0f; slot_col[j] = 0; }
    __syncthreads();

    if (tid < 32) {  // one thread per bank spreads its entries across chunks
        int k = 0;
        const int n = (cnt < KSLOTS) ? cnt : KSLOTS;
        for (int p = 0; p < n; ++p) {
            int c = scol[p];
            if ((c & 31) == tid) {
                int ch0 = (k + tid) % CHUNKS;
                for (int probe = 0; probe < CHUNKS; ++probe) {
                    int cc = ch0 + probe; if (cc >= CHUNKS) cc -= CHUNKS;
                    int pos = atomicAdd(&chunk_fill[cc], 1);
                    if (pos < 64) {
                        slot_val[cc * 64 + pos] = sval[p];
                        slot_col[cc * 64 + pos] = (unsigned short)c;
                        break;
                    }
                }
                ++k;
            }
        }
    }
    __syncthreads();

    float* vrow = vals + (size_t)r * KSLOTS;
    unsigned short* crow = cols + (size_t)r * KSLOTS;
    for (int j = tid; j < KSLOTS; j += blockDim.x) { vrow[j] = slot_val[j]; crow[j] = slot_col[j]; }
}

// ---------------------------------------------------------------------------
// Coherent 16B accesses straight at the coherence point (bypass L1+L2).
// Load form is R4/R9-proven (passed full harness incl. replay tripwires).
// ---------------------------------------------------------------------------
__device__ __forceinline__ f32x4 load_coherent_x4(const float* p) {
    f32x4 v;
    asm volatile("global_load_dwordx4 %0, %1, off sc0 sc1\n\t"
                 "s_waitcnt vmcnt(0)"
                 : "=v"(v) : "v"(p) : "memory");
    return v;
}

__device__ __forceinline__ void store_coherent_x4(float* p, f32x4 v) {
    asm volatile("global_store_dwordx4 %0, %1, off sc0 sc1"
                 :: "v"(p), "v"(v) : "memory");
}

__device__ __forceinline__ bool granule_not_ready(f32x4 hv) {
    return (__float_as_uint(hv.x) == SENTINEL_BITS) |
           (__float_as_uint(hv.y) == SENTINEL_BITS) |
           (__float_as_uint(hv.z) == SENTINEL_BITS) |
           (__float_as_uint(hv.w) == SENTINEL_BITS);
}

// Branch-free tanh (validated R6-first-launch + R9: absmax 3.9e-3 unchanged).
__device__ __forceinline__ float fast_tanh(float v) {
    float ax = __builtin_fabsf(v);
    float e  = __builtin_amdgcn_exp2f(ax * 2.88539008177793f);  // 2*log2(e)
    float r  = 1.0f - 2.0f * __builtin_amdgcn_rcpf(e + 1.0f);
    return __builtin_copysignf(r, v);
}

// ---------------------------------------------------------------------------
// R19: full 64-lane sum via the canonical GCN DPP ladder — row_shr 1/2/4/8
// then row_bcast15 (rows 1,3) and row_bcast31 (rows 2,3). Pure VALU: moves
// the reduction OFF the LDS pipe (shfl_xor = ds_bpermute on CDNA). Lane 63
// holds the total. bound_ctrl=true zero-fills invalid source lanes; masked
// rows keep old=0 so the add is a no-op there. All 64 lanes are active at
// the call sites (uniform control flow).
// ---------------------------------------------------------------------------
__device__ __forceinline__ float dpp_reduce_add(float v) {
    int t;
    t = __builtin_amdgcn_update_dpp(0, __float_as_int(v), 0x111, 0xf, 0xf, true); // shr:1
    v += __int_as_float(t);
    t = __builtin_amdgcn_update_dpp(0, __float_as_int(v), 0x112, 0xf, 0xf, true); // shr:2
    v += __int_as_float(t);
    t = __builtin_amdgcn_update_dpp(0, __float_as_int(v), 0x114, 0xf, 0xf, true); // shr:4
    v += __int_as_float(t);
    t = __builtin_amdgcn_update_dpp(0, __float_as_int(v), 0x118, 0xf, 0xf, true); // shr:8
    v += __int_as_float(t);
    t = __builtin_amdgcn_update_dpp(0, __float_as_int(v), 0x142, 0xa, 0xf, true); // bcast15
    v += __int_as_float(t);
    t = __builtin_amdgcn_update_dpp(0, __float_as_int(v), 0x143, 0xc, 0xf, true); // bcast31
    v += __int_as_float(t);
    return v;   // lane 63 = sum over all 64 lanes
}

// ---------------------------------------------------------------------------
// Kernel 2: persistent step kernel — R13's proven skeleton and sync
// semantics byte-identical (128 blocks, 2 rows/wave, qNaN data-as-flag,
// R13 paced poll ladder, hout collect, wave-0 full-line sc0 sc1 store).
// R19 changes target the LDS pipe, which the counter arithmetic shows is
// ~70% occupied per step (gather 1670cy + shfl-as-bpermute 1150cy +
// staging/x 380cy + 415cy measured bank-conflict overhead vs 5070cy step):
//   1. butterfly __shfl_xor reduce -> DPP VALU ladder  (-~1150cy LDS pipe)
//   2. x_t read directly via cached global loads (L1 broadcast across the
//      16 waves; x is L2-resident, no HBM delta)      (-~190cy LDS pipe)
// Poll/store/visibility paths untouched (R18 dual-slot reverted: flat).
// ---------------------------------------------------------------------------
__global__ void __launch_bounds__(NTHREADS, 1) esn_steps(
    const float* __restrict__ x,
    const float* __restrict__ W_in,
    const float* __restrict__ vals,
    const unsigned short* __restrict__ cols,
    float* __restrict__ out) {

    __shared__ float h_lds[N];       // full previous state, 16 KB
    __shared__ __align__(16) float hout[ROWS_PER_BLOCK];  // block's 32 new rows

    const int tid  = threadIdx.x;
    const int lane = tid & 63;
    const int wave = tid >> 6;
    const int blockBase = blockIdx.x * ROWS_PER_BLOCK;
    const int base = blockBase + wave * ROWS_PER_WAVE;  // 2 rows/wave

    // Per-row W_in slices.
    float w0[ROWS_PER_WAVE], w1[ROWS_PER_WAVE];
    #pragma unroll
    for (int j = 0; j < ROWS_PER_WAVE; ++j) {
        w0[j] = W_in[(base + j) * IN_DIM + lane];
        w1[j] = W_in[(base + j) * IN_DIM + 64 + lane];
    }

    // Hoist the 2-row ELL slice into registers (18 vals + 18 byte offsets).
    float rv[ROWS_PER_WAVE][CHUNKS];
    int   rc[ROWS_PER_WAVE][CHUNKS];
    #pragma unroll
    for (int j = 0; j < ROWS_PER_WAVE; ++j) {
        const float* vp = vals + (size_t)(base + j) * KSLOTS;
        const unsigned short* cp = cols + (size_t)(base + j) * KSLOTS;
        #pragma unroll
        for (int i = 0; i < CHUNKS; ++i) {
            rv[j][i] = vp[(i << 6) + lane];
            rc[j][i] = ((int)cp[(i << 6) + lane]) << 2;
        }
    }

    const int i4 = tid << 2;

    for (int t = 0; t < T_STEPS; ++t) {
        // ---- x_t via cached global loads (L1 broadcast; issued before the
        //      poll so the latency hides under sleep(8)+ladder) ----
        const float xa = x[t * IN_DIM + lane];
        const float xb = x[t * IN_DIM + 64 + lane];

        // ---- stage h_{t-1}: R13 paced coherent dwordx4 poll (proven) ----
        f32x4 hv;
        if (t > 0) {
            const float* addr = out + (size_t)(t - 1) * N + i4;
            __builtin_amdgcn_s_sleep(8);           // skip guaranteed-miss round
            hv = load_coherent_x4(addr);
            if (granule_not_ready(hv)) {
                __builtin_amdgcn_s_sleep(1);
                hv = load_coherent_x4(addr);
                if (granule_not_ready(hv)) {
                    __builtin_amdgcn_s_sleep(2);
                    hv = load_coherent_x4(addr);
                    while (granule_not_ready(hv)) {
                        __builtin_amdgcn_s_sleep(4);   // steady 256cy cap
                        hv = load_coherent_x4(addr);
                    }
                }
            }
        } else {
            hv = (f32x4)(0.0f);
        }
        ((f32x4*)h_lds)[tid] = hv;
        __syncthreads();   // barrier 1: h_lds fully staged

        // ---- 2 row dots: input part + register-ELL sparse gather ----
        float acc[ROWS_PER_WAVE];
        #pragma unroll
        for (int j = 0; j < ROWS_PER_WAVE; ++j) acc[j] = w0[j] * xa + w1[j] * xb;

        #pragma unroll
        for (int j = 0; j < ROWS_PER_WAVE; ++j) {
            #pragma unroll
            for (int i = 0; i < CHUNKS; ++i) {
                acc[j] += rv[j][i] * *(const float*)((const char*)h_lds + rc[j][i]);
            }
        }

        // ---- DPP reduce (VALU pipe, not LDS): lane 63 holds both sums ----
        acc[0] = dpp_reduce_add(acc[0]);
        acc[1] = dpp_reduce_add(acc[1]);

        // lane 63 finalizes both rows into the LDS collect buffer
        if (lane == 63) {
            float hp0 = h_lds[base + 0];
            float hp1 = h_lds[base + 1];
            hout[wave * ROWS_PER_WAVE + 0] = 0.7f * hp0 + 0.3f * fast_tanh(acc[0]);
            hout[wave * ROWS_PER_WAVE + 1] = 0.7f * hp1 + 0.3f * fast_tanh(acc[1]);
        }
        __syncthreads();   // barrier 2: collect done + all h_lds reads done

        // ---- wave 0 emits the block's 32 rows as one coalesced 128B store;
        //      the other 15 waves proceed straight to the next step's poll ----
        if (tid < ROWS_PER_BLOCK / 4) {
            f32x4 hv4 = ((const f32x4*)hout)[tid];
            store_coherent_x4(out + (size_t)t * N + blockBase + (tid << 2), hv4);
        }
    }
}

// ---------------------------------------------------------------------------
// Workspace layout (bytes):
//   [0, +N*KSLOTS*4)       ELL vals (f32)   9.44 MB
//   [.., +N*KSLOTS*2)      ELL cols (u16)   4.72 MB
// ---------------------------------------------------------------------------
extern "C" void kernel_launch(void* const* d_in, const int* in_sizes, int n_in,
                              void* d_out, int out_size, void* d_ws, size_t ws_size,
                              hipStream_t stream) {
    const float* x    = (const float*)d_in[0];  // [2048,128]
    const float* W_in = (const float*)d_in[1];  // [4096,128]
    const float* W    = (const float*)d_in[2];  // [4096,4096]
    float* out = (float*)d_out;                 // [2048,4096]

    char* ws = (char*)d_ws;
    float* vals = (float*)ws;
    unsigned short* cols = (unsigned short*)(ws + (size_t)N * KSLOTS * 4);

    init_sentinel<<<(T_STEPS * N) / NTHREADS, NTHREADS, 0, stream>>>(out);
    build_ell<<<N, 256, 0, stream>>>(W, vals, cols);

    void* args[] = {(void*)&x, (void*)&W_in, (void*)&vals, (void*)&cols, (void*)&out};
    hipLaunchCooperativeKernel((void*)esn_steps, dim3(NBLOCKS), dim3(NTHREADS),
                               args, 0, stream);
}